// Round 1
// baseline (19.919 us; speedup 1.0000x reference)
//
#include <hip/hip_runtime.h>
#include <math.h>

#define BATCH 16
#define NPTS 17
#define MPTS 4096
#define NPAIR 136          // 17*16/2, pairs (i>j)
#define CNT 5
#define MAXDIS 1e-3f
#define EPS_ABS 1e-5f

// Kernel 1: one block per (batch, pair). 256 threads stripe over the 4096
// gt points, keep 5 running mins (one per interpolation point), block-reduce,
// thread 0 emits (cos_term, mask_count) for this pair into ws.
__global__ __launch_bounds__(256) void pair_kernel(const float* __restrict__ recon,
                                                   const float* __restrict__ gt,
                                                   float* __restrict__ ws) {
    const int blk = blockIdx.x;            // b*NPAIR + p
    const int b = blk / NPAIR;
    const int p = blk - b * NPAIR;
    // decode pair index p -> (i, j), i in [1,16], j < i, p = i*(i-1)/2 + j
    int i = 1;
    while ((i * (i + 1)) / 2 <= p) ++i;
    const int j = p - (i * (i - 1)) / 2;

    const float* rp = recon + (size_t)b * NPTS * 2;
    const float pix = rp[2 * i], piy = rp[2 * i + 1];
    const float pjx = rp[2 * j], pjy = rp[2 * j + 1];

    // K_c = p_i * t_c + p_j * (1 - t_c), t = {0, .25, .5, .75, 1}
    float Kx[CNT], Ky[CNT], k2[CNT], mn[CNT];
    #pragma unroll
    for (int c = 0; c < CNT; ++c) {
        const float t = 0.25f * (float)c;
        const float omt = 1.0f - t;
        Kx[c] = pix * t + pjx * omt;
        Ky[c] = piy * t + pjy * omt;
        k2[c] = Kx[c] * Kx[c] + Ky[c] * Ky[c];
        mn[c] = 1e30f;
    }

    // stripe over gt points, float4 = 2 points per load
    const float4* g4 = (const float4*)(gt + (size_t)b * MPTS * 2);
    for (int q = threadIdx.x; q < MPTS / 2; q += 256) {
        const float4 g = g4[q];
        const float g2a = g.x * g.x + g.y * g.y;
        const float g2b = g.z * g.z + g.w * g.w;
        #pragma unroll
        for (int c = 0; c < CNT; ++c) {
            // mirror reference: (k2 + g2) - 2*cross
            const float da = (k2[c] + g2a) - 2.0f * (Kx[c] * g.x + Ky[c] * g.y);
            const float db = (k2[c] + g2b) - 2.0f * (Kx[c] * g.z + Ky[c] * g.w);
            mn[c] = fminf(mn[c], fminf(da, db));
        }
    }

    // wave (64-lane) shuffle reduce
    #pragma unroll
    for (int c = 0; c < CNT; ++c) {
        #pragma unroll
        for (int off = 32; off > 0; off >>= 1)
            mn[c] = fminf(mn[c], __shfl_down(mn[c], off, 64));
    }
    __shared__ float smin[4][CNT];
    const int wave = threadIdx.x >> 6, lane = threadIdx.x & 63;
    if (lane == 0) {
        #pragma unroll
        for (int c = 0; c < CNT; ++c) smin[wave][c] = mn[c];
    }
    __syncthreads();

    if (threadIdx.x == 0) {
        float acc[CNT];
        #pragma unroll
        for (int c = 0; c < CNT; ++c) {
            float v = smin[0][c];
            v = fminf(v, smin[1][c]);
            v = fminf(v, smin[2][c]);
            v = fminf(v, smin[3][c]);
            acc[c] = v;
        }
        // mean over C: ((((m0+m1)+m2)+m3)+m4)/5
        const float cdis = ((((acc[0] + acc[1]) + acc[2]) + acc[3]) + acc[4]) / 5.0f;

        float cosv = 0.0f, cntv = 0.0f;
        if (cdis < MAXDIS) {
            const float u0x = rp[0], u0y = rp[1];
            const float uix = u0x - pix, uiy = u0y - piy;
            const float ujx = u0x - pjx, ujy = u0y - pjy;
            const float dot = fabsf(uix * ujx + uiy * ujy);
            // reference: sqrt((ux^2+eps) + (uy^2+eps))
            const float ai = sqrtf((uix * uix + EPS_ABS) + (uiy * uiy + EPS_ABS));
            const float aj = sqrtf((ujx * ujx + EPS_ABS) + (ujy * ujy + EPS_ABS));
            cosv = dot / (ai * aj);
            cntv = 1.0f;
        }
        ws[2 * blk] = cosv;
        ws[2 * blk + 1] = cntv;
    }
}

// Kernel 2: deterministic reduction of the 2176 (cos, cnt) pairs -> scalar.
__global__ __launch_bounds__(256) void reduce_kernel(const float* __restrict__ ws,
                                                     float* __restrict__ out) {
    __shared__ float scos[256];
    __shared__ float scnt[256];
    float c = 0.0f, n = 0.0f;
    for (int k = threadIdx.x; k < BATCH * NPAIR; k += 256) {
        c += ws[2 * k];
        n += ws[2 * k + 1];
    }
    scos[threadIdx.x] = c;
    scnt[threadIdx.x] = n;
    __syncthreads();
    for (int s = 128; s > 0; s >>= 1) {
        if (threadIdx.x < (unsigned)s) {
            scos[threadIdx.x] += scos[threadIdx.x + s];
            scnt[threadIdx.x] += scnt[threadIdx.x + s];
        }
        __syncthreads();
    }
    if (threadIdx.x == 0) out[0] = scos[0] / (1.0f + scnt[0]);
}

extern "C" void kernel_launch(void* const* d_in, const int* in_sizes, int n_in,
                              void* d_out, int out_size, void* d_ws, size_t ws_size,
                              hipStream_t stream) {
    const float* recon = (const float*)d_in[0];  // [16,17,2] f32
    const float* gt = (const float*)d_in[1];     // [16,4096,2] f32
    float* out = (float*)d_out;                  // scalar f32
    float* ws = (float*)d_ws;                    // 2176*2 floats

    pair_kernel<<<BATCH * NPAIR, 256, 0, stream>>>(recon, gt, ws);
    reduce_kernel<<<1, 256, 0, stream>>>(ws, out);
}